// Round 1
// baseline (548.888 us; speedup 1.0000x reference)
//
#include <hip/hip_runtime.h>
#include <stdint.h>

// EfficientDet post-process: score max/argmax -> top-1000 select -> sort -> NMS.
// Constants match the reference problem exactly.
#define A_NUM   49104
#define BATCH   8
#define NCLS    90
#define KSEL    1000
#define SCORE_T 0.05f
#define IOU_T   0.5f
#define IMG_F   512.0f

#define NBINS   256
#define NCOPIES 16

// ---- unique 48-bit descending key: (monotonic score bits << 16) | (0xFFFF - a)
// Positive floats map above negative (-1.0 masked scores); index term gives
// jax.lax.top_k's lower-index-first tie break. All keys unique (index unique).
__device__ __forceinline__ uint64_t make_key(float s, int a) {
    uint32_t u = __float_as_uint(s);
    u = (u & 0x80000000u) ? ~u : (u | 0x80000000u);
    return ((uint64_t)u << 16) | (uint64_t)(0xFFFFu - (uint32_t)a);
}

// ---- kernel 1: per-anchor class max + argmax (first-max tie break), mask <= T to -1
__global__ void score_kernel(const float* __restrict__ cls,
                             float* __restrict__ scores,
                             int* __restrict__ classes) {
    int i = blockIdx.x * blockDim.x + threadIdx.x;
    const int BA = BATCH * A_NUM;
    if (i >= BA) return;
    const float* row = cls + (size_t)i * NCLS;   // 360B rows, 8B aligned
    float best = -1e30f; int bc = 0;
    #pragma unroll 9
    for (int c = 0; c < NCLS; c += 2) {
        float2 v = *reinterpret_cast<const float2*>(row + c);
        if (v.x > best) { best = v.x; bc = c; }
        if (v.y > best) { best = v.y; bc = c + 1; }
    }
    scores[i]  = (best > SCORE_T) ? best : -1.0f;
    classes[i] = bc;
}

// ---- kernel 2: per-image radix select of the exact 1000th-largest 48-bit key
__global__ void __launch_bounds__(1024) select_kernel(const float* __restrict__ scores,
                                                      uint64_t* __restrict__ kstar,
                                                      int* __restrict__ counters,
                                                      uint64_t* __restrict__ selkeys) {
    __shared__ uint32_t hist[NCOPIES][NBINS];
    __shared__ uint32_t cum[NBINS];
    __shared__ uint64_t sh_prefix;
    __shared__ uint32_t sh_target;
    const int b   = blockIdx.x;
    const int tid = threadIdx.x;
    const int wid = tid >> 6;                    // wave id (16 waves)
    const float* sc = scores + (size_t)b * A_NUM;
    if (tid == 0) { sh_prefix = 0; sh_target = KSEL; }
    __syncthreads();
    for (int pass = 0; pass < 6; ++pass) {
        const int shift = 40 - 8 * pass;
        for (int t = tid; t < NCOPIES * NBINS; t += 1024) ((uint32_t*)hist)[t] = 0;
        __syncthreads();
        const uint64_t prefix = sh_prefix;
        const uint32_t target = sh_target;
        for (int i = tid; i < A_NUM; i += 1024) {
            uint64_t k = make_key(sc[i], i);
            if ((k >> (shift + 8)) == prefix)
                atomicAdd(&hist[wid][(k >> shift) & 0xFF], 1u);
        }
        __syncthreads();
        if (tid < NBINS) {
            uint32_t s = 0;
            #pragma unroll
            for (int c = 0; c < NCOPIES; ++c) s += hist[c][tid];
            cum[tid] = s;
        }
        __syncthreads();
        // suffix sum: cum[t] = count of keys in bins >= t (within prefix)
        for (int off = 1; off < NBINS; off <<= 1) {
            uint32_t v = 0;
            if (tid < NBINS) {
                v = cum[tid];
                if (tid + off < NBINS) v += cum[tid + off];
            }
            __syncthreads();
            if (tid < NBINS) cum[tid] = v;
            __syncthreads();
        }
        if (tid < NBINS) {
            uint32_t c  = cum[tid];
            uint32_t cn = (tid < NBINS - 1) ? cum[tid + 1] : 0;
            if (c >= target && cn < target) {       // unique boundary bin
                sh_prefix = (prefix << 8) | (uint64_t)tid;
                sh_target = target - cn;
            }
        }
        __syncthreads();
    }
    if (tid == 0) { kstar[b] = sh_prefix; counters[b] = 0; }
    if (tid < 1024 - KSEL) selkeys[b * 1024 + KSEL + tid] = 0;  // pad for bitonic
}

// ---- kernel 3: compact exactly the 1000 keys >= K* (unordered)
__global__ void compact_kernel(const float* __restrict__ scores,
                               const uint64_t* __restrict__ kstar,
                               int* __restrict__ counters,
                               uint64_t* __restrict__ selkeys) {
    int i = blockIdx.x * blockDim.x + threadIdx.x;
    const int BA = BATCH * A_NUM;
    if (i >= BA) return;
    int b = i / A_NUM;
    int a = i - b * A_NUM;
    uint64_t k = make_key(scores[i], a);
    if (k >= kstar[b]) {
        int pos = atomicAdd(&counters[b], 1);
        selkeys[b * 1024 + pos] = k;
    }
}

// ---- kernel 4: bitonic sort 1024 keys descending; decode + emit boxes/scores/labels
__global__ void __launch_bounds__(1024) sort_emit_kernel(const uint64_t* __restrict__ selkeys,
                                                         const float* __restrict__ scores,
                                                         const int* __restrict__ classes,
                                                         const float* __restrict__ anchors,
                                                         const float* __restrict__ regression,
                                                         float* __restrict__ out) {
    __shared__ uint64_t keys[1024];
    const int b   = blockIdx.x;
    const int tid = threadIdx.x;
    keys[tid] = selkeys[b * 1024 + tid];
    __syncthreads();
    for (int k = 2; k <= 1024; k <<= 1) {
        for (int j = k >> 1; j > 0; j >>= 1) {
            int partner = tid ^ j;
            if (partner > tid) {
                uint64_t a0 = keys[tid], a1 = keys[partner];
                bool up = ((tid & k) == 0);             // descending overall
                bool sw = up ? (a0 < a1) : (a0 > a1);
                if (sw) { keys[tid] = a1; keys[partner] = a0; }
            }
            __syncthreads();
        }
    }
    if (tid < KSEL) {
        uint64_t key = keys[tid];
        int a = 0xFFFF - (int)(key & 0xFFFFu);
        size_t gi = (size_t)b * A_NUM + a;
        float s = scores[gi];
        int   c = classes[gi];
        const float* an = anchors + (size_t)a * 4;
        const float* rg = regression + gi * 4;
        float y1a = an[0], x1a = an[1], y2a = an[2], x2a = an[3];
        float ya = (y1a + y2a) * 0.5f, xa = (x1a + x2a) * 0.5f;
        float ha = y2a - y1a,          wa = x2a - x1a;
        float r0 = rg[0], r1 = rg[1], r2 = rg[2], r3 = rg[3];
        float w  = expf(r3) * wa;
        float h  = expf(r2) * ha;
        float yc = r0 * ha + ya;
        float xc = r1 * wa + xa;
        float x1 = fmaxf(xc - w * 0.5f, 0.0f);
        float y1 = fmaxf(yc - h * 0.5f, 0.0f);
        float x2 = fminf(xc + w * 0.5f, IMG_F);
        float y2 = fminf(yc + h * 0.5f, IMG_F);
        int o = b * KSEL + tid;
        out[(size_t)o * 4 + 0] = x1;
        out[(size_t)o * 4 + 1] = y1;
        out[(size_t)o * 4 + 2] = x2;
        out[(size_t)o * 4 + 3] = y2;
        out[BATCH * KSEL * 4 + o]                 = s;             // scores
        out[BATCH * KSEL * 4 + BATCH * KSEL + o]  = (float)(c + 1);// labels
    }
}

// ---- kernel 5: class-aware greedy NMS over the sorted 1000, one block/image
__global__ void __launch_bounds__(1024) nms_kernel(float* __restrict__ out) {
    __shared__ float bx[KSEL][4];
    __shared__ int   scl[KSEL];
    __shared__ int   keep[1024];
    const int b   = blockIdx.x;
    const int tid = threadIdx.x;
    const int score_off = BATCH * KSEL * 4;
    const int label_off = score_off + BATCH * KSEL;
    const int keep_off  = label_off + BATCH * KSEL;
    if (tid < KSEL) {
        int o = b * KSEL + tid;
        float4 v = *reinterpret_cast<const float4*>(out + (size_t)o * 4);
        bx[tid][0] = v.x; bx[tid][1] = v.y; bx[tid][2] = v.z; bx[tid][3] = v.w;
        scl[tid]  = (int)out[label_off + o];
        keep[tid] = (out[score_off + o] > SCORE_T) ? 1 : 0;
    } else {
        keep[tid] = 0;
    }
    __syncthreads();
    float mx1 = 0, my1 = 0, mx2 = 0, my2 = 0, marea = 0; int mcl = -1;
    if (tid < KSEL) {
        mx1 = bx[tid][0]; my1 = bx[tid][1]; mx2 = bx[tid][2]; my2 = bx[tid][3];
        marea = (mx2 - mx1) * (my2 - my1);
        mcl = scl[tid];
    }
    for (int i = 0; i < KSEL - 1; ++i) {
        __syncthreads();
        if (!keep[i]) continue;                       // uniform branch
        float ix1 = bx[i][0], iy1 = bx[i][1], ix2 = bx[i][2], iy2 = bx[i][3];
        float iarea = (ix2 - ix1) * (iy2 - iy1);
        if (tid > i && tid < KSEL && keep[tid] && scl[i] == mcl) {
            float lx = fmaxf(ix1, mx1), ly = fmaxf(iy1, my1);
            float rx = fminf(ix2, mx2), ry = fminf(iy2, my2);
            float iw = fmaxf(rx - lx, 0.0f), ih = fmaxf(ry - ly, 0.0f);
            float inter = iw * ih;
            float iou = inter / (iarea + marea - inter + 1e-8f);
            if (iou > IOU_T) keep[tid] = 0;
        }
    }
    __syncthreads();
    if (tid < KSEL) out[keep_off + b * KSEL + tid] = keep[tid] ? 1.0f : 0.0f;
}

extern "C" void kernel_launch(void* const* d_in, const int* in_sizes, int n_in,
                              void* d_out, int out_size, void* d_ws, size_t ws_size,
                              hipStream_t stream) {
    const float* anchors        = (const float*)d_in[1];
    const float* regression     = (const float*)d_in[2];
    const float* classification = (const float*)d_in[3];
    float* out = (float*)d_out;

    char* ws = (char*)d_ws;
    const size_t BA = (size_t)BATCH * A_NUM;          // 392832
    float*    scores   = (float*)ws;                  // 1,571,328 B
    int*      classes  = (int*)(ws + 1571328);        // 1,571,328 B
    uint64_t* selkeys  = (uint64_t*)(ws + 3142656);   // 65,536 B
    uint64_t* kstar    = (uint64_t*)(ws + 3208192);   // 64 B
    int*      counters = (int*)(ws + 3208256);        // 32 B

    int nblk = (int)((BA + 255) / 256);
    score_kernel<<<nblk, 256, 0, stream>>>(classification, scores, classes);
    select_kernel<<<BATCH, 1024, 0, stream>>>(scores, kstar, counters, selkeys);
    compact_kernel<<<nblk, 256, 0, stream>>>(scores, kstar, counters, selkeys);
    sort_emit_kernel<<<BATCH, 1024, 0, stream>>>(selkeys, scores, classes, anchors,
                                                 regression, out);
    nms_kernel<<<BATCH, 1024, 0, stream>>>(out);
}

// Round 2
// 314.118 us; speedup vs baseline: 1.7474x; 1.7474x over previous
//
#include <hip/hip_runtime.h>
#include <stdint.h>

// EfficientDet post-process: score max/argmax -> top-1000 select -> sort -> NMS.
#define A_NUM   49104
#define BATCH   8
#define NCLS    90
#define KSEL    1000
#define SCORE_T 0.05f
#define IOU_T   0.5f
#define IMG_F   512.0f

#define NBINS   256
#define NCOPIES 16

// ---- unique 48-bit descending key: (monotonic score bits << 16) | (0xFFFF - a)
__device__ __forceinline__ uint64_t make_key(float s, int a) {
    uint32_t u = __float_as_uint(s);
    u = (u & 0x80000000u) ? ~u : (u | 0x80000000u);
    return ((uint64_t)u << 16) | (uint64_t)(0xFFFFu - (uint32_t)a);
}

// ---- kernel 1: per-anchor class max + argmax, mask <= T to -1
__global__ void score_kernel(const float* __restrict__ cls,
                             float* __restrict__ scores,
                             int* __restrict__ classes) {
    int i = blockIdx.x * blockDim.x + threadIdx.x;
    const int BA = BATCH * A_NUM;
    if (i >= BA) return;
    const float* row = cls + (size_t)i * NCLS;
    float best = -1e30f; int bc = 0;
    #pragma unroll 9
    for (int c = 0; c < NCLS; c += 2) {
        float2 v = *reinterpret_cast<const float2*>(row + c);
        if (v.x > best) { best = v.x; bc = c; }
        if (v.y > best) { best = v.y; bc = c + 1; }
    }
    scores[i]  = (best > SCORE_T) ? best : -1.0f;
    classes[i] = bc;
}

// ---- kernel 2: per-image radix select of the exact 1000th-largest 48-bit key
__global__ void __launch_bounds__(1024) select_kernel(const float* __restrict__ scores,
                                                      uint64_t* __restrict__ kstar,
                                                      int* __restrict__ counters,
                                                      uint64_t* __restrict__ selkeys) {
    __shared__ uint32_t hist[NCOPIES][NBINS];
    __shared__ uint32_t cum[NBINS];
    __shared__ uint64_t sh_prefix;
    __shared__ uint32_t sh_target;
    const int b   = blockIdx.x;
    const int tid = threadIdx.x;
    const int wid = tid >> 6;
    const float* sc = scores + (size_t)b * A_NUM;
    if (tid == 0) { sh_prefix = 0; sh_target = KSEL; }
    __syncthreads();
    for (int pass = 0; pass < 6; ++pass) {
        const int shift = 40 - 8 * pass;
        for (int t = tid; t < NCOPIES * NBINS; t += 1024) ((uint32_t*)hist)[t] = 0;
        __syncthreads();
        const uint64_t prefix = sh_prefix;
        const uint32_t target = sh_target;
        for (int i = tid; i < A_NUM; i += 1024) {
            uint64_t k = make_key(sc[i], i);
            if ((k >> (shift + 8)) == prefix)
                atomicAdd(&hist[wid][(k >> shift) & 0xFF], 1u);
        }
        __syncthreads();
        if (tid < NBINS) {
            uint32_t s = 0;
            #pragma unroll
            for (int c = 0; c < NCOPIES; ++c) s += hist[c][tid];
            cum[tid] = s;
        }
        __syncthreads();
        for (int off = 1; off < NBINS; off <<= 1) {
            uint32_t v = 0;
            if (tid < NBINS) {
                v = cum[tid];
                if (tid + off < NBINS) v += cum[tid + off];
            }
            __syncthreads();
            if (tid < NBINS) cum[tid] = v;
            __syncthreads();
        }
        if (tid < NBINS) {
            uint32_t c  = cum[tid];
            uint32_t cn = (tid < NBINS - 1) ? cum[tid + 1] : 0;
            if (c >= target && cn < target) {
                sh_prefix = (prefix << 8) | (uint64_t)tid;
                sh_target = target - cn;
            }
        }
        __syncthreads();
    }
    if (tid == 0) { kstar[b] = sh_prefix; counters[b] = 0; }
    if (tid < 1024 - KSEL) selkeys[b * 1024 + KSEL + tid] = 0;
}

// ---- kernel 3: compact exactly the 1000 keys >= K* (unordered)
__global__ void compact_kernel(const float* __restrict__ scores,
                               const uint64_t* __restrict__ kstar,
                               int* __restrict__ counters,
                               uint64_t* __restrict__ selkeys) {
    int i = blockIdx.x * blockDim.x + threadIdx.x;
    const int BA = BATCH * A_NUM;
    if (i >= BA) return;
    int b = i / A_NUM;
    int a = i - b * A_NUM;
    uint64_t k = make_key(scores[i], a);
    if (k >= kstar[b]) {
        int pos = atomicAdd(&counters[b], 1);
        selkeys[b * 1024 + pos] = k;
    }
}

// ---- kernel 4: bitonic sort 1024 keys descending; decode + emit; valid bitmask
__global__ void __launch_bounds__(1024) sort_emit_kernel(const uint64_t* __restrict__ selkeys,
                                                         const float* __restrict__ scores,
                                                         const int* __restrict__ classes,
                                                         const float* __restrict__ anchors,
                                                         const float* __restrict__ regression,
                                                         float* __restrict__ out,
                                                         uint64_t* __restrict__ validw) {
    __shared__ uint64_t keys[1024];
    const int b   = blockIdx.x;
    const int tid = threadIdx.x;
    keys[tid] = selkeys[b * 1024 + tid];
    __syncthreads();
    for (int k = 2; k <= 1024; k <<= 1) {
        for (int j = k >> 1; j > 0; j >>= 1) {
            int partner = tid ^ j;
            if (partner > tid) {
                uint64_t a0 = keys[tid], a1 = keys[partner];
                bool up = ((tid & k) == 0);
                bool sw = up ? (a0 < a1) : (a0 > a1);
                if (sw) { keys[tid] = a1; keys[partner] = a0; }
            }
            __syncthreads();
        }
    }
    float sval = -1.0f;
    if (tid < KSEL) {
        uint64_t key = keys[tid];
        int a = 0xFFFF - (int)(key & 0xFFFFu);
        size_t gi = (size_t)b * A_NUM + a;
        float s = scores[gi];
        int   c = classes[gi];
        const float* an = anchors + (size_t)a * 4;
        const float* rg = regression + gi * 4;
        float y1a = an[0], x1a = an[1], y2a = an[2], x2a = an[3];
        float ya = (y1a + y2a) * 0.5f, xa = (x1a + x2a) * 0.5f;
        float ha = y2a - y1a,          wa = x2a - x1a;
        float r0 = rg[0], r1 = rg[1], r2 = rg[2], r3 = rg[3];
        float w  = expf(r3) * wa;
        float h  = expf(r2) * ha;
        float yc = r0 * ha + ya;
        float xc = r1 * wa + xa;
        float x1 = fmaxf(xc - w * 0.5f, 0.0f);
        float y1 = fmaxf(yc - h * 0.5f, 0.0f);
        float x2 = fminf(xc + w * 0.5f, IMG_F);
        float y2 = fminf(yc + h * 0.5f, IMG_F);
        int o = b * KSEL + tid;
        out[(size_t)o * 4 + 0] = x1;
        out[(size_t)o * 4 + 1] = y1;
        out[(size_t)o * 4 + 2] = x2;
        out[(size_t)o * 4 + 3] = y2;
        out[BATCH * KSEL * 4 + o]                = s;
        out[BATCH * KSEL * 4 + BATCH * KSEL + o] = (float)(c + 1);
        sval = s;
    }
    unsigned long long vm = __ballot(sval > SCORE_T);
    if ((tid & 63) == 0) validw[b * 16 + (tid >> 6)] = vm;
}

// ---- kernel 5a: suppression bitmask matrix. sup[b][i][w] = 64-bit word over
// j = w*64..w*64+63 of (j>i && same class && iou>IOU_T). One wave per (i,w) row
// group; lane = j offset -> coalesced LDS reads + __ballot, no serial deps.
__global__ void __launch_bounds__(256) supmat_kernel(const float* __restrict__ out,
                                                     uint64_t* __restrict__ supmat) {
    __shared__ float4 sbox[KSEL];
    __shared__ float  sarea[KSEL];
    __shared__ int    scls[KSEL];
    const int g    = blockIdx.x;       // 0..62 (16 i's each)
    const int b    = blockIdx.y;
    const int tid  = threadIdx.x;
    const int lane = tid & 63;
    const int wv   = tid >> 6;
    const int label_off = BATCH * KSEL * 4 + BATCH * KSEL;
    for (int j = tid; j < KSEL; j += 256) {
        float4 v = *reinterpret_cast<const float4*>(out + (size_t)(b * KSEL + j) * 4);
        sbox[j]  = v;
        sarea[j] = (v.z - v.x) * (v.w - v.y);
        scls[j]  = (int)out[label_off + b * KSEL + j];
    }
    __syncthreads();
    #pragma unroll
    for (int q = 0; q < 4; ++q) {
        int i = g * 16 + wv * 4 + q;
        if (i >= KSEL) continue;                 // wave-uniform
        float4 bi = sbox[i];
        float  ai = sarea[i];
        int    ci = scls[i];
        uint64_t* dst = supmat + ((size_t)b * 1024 + i) * 16;
        #pragma unroll
        for (int w = 0; w < 16; ++w) {
            int j = w * 64 + lane;
            bool sup = false;
            if (j > i && j < KSEL) {
                float4 bj = sbox[j];
                float lx = fmaxf(bi.x, bj.x), ly = fmaxf(bi.y, bj.y);
                float rx = fminf(bi.z, bj.z), ry = fminf(bi.w, bj.w);
                float iw = fmaxf(rx - lx, 0.0f), ih = fmaxf(ry - ly, 0.0f);
                float inter = iw * ih;
                float iou = inter / (ai + sarea[j] - inter + 1e-8f);
                sup = (iou > IOU_T) && (ci == scls[j]);
            }
            unsigned long long m = __ballot(sup);
            if (lane == 0) dst[w] = m;
        }
    }
}

// ---- kernel 5b: serial greedy scan, one wave per image, no barriers.
// Lane l (0..15) owns keep word l; 16-deep register prefetch ring hides L2.
__global__ void __launch_bounds__(64) scan_kernel(const uint64_t* __restrict__ supmat,
                                                  const uint64_t* __restrict__ validw,
                                                  float* __restrict__ out) {
    const int b    = blockIdx.x;
    const int lane = threadIdx.x;
    const int w16  = lane & 15;
    uint64_t keep = validw[b * 16 + w16];        // lanes >=16 mirror lane&15
    const uint64_t* row = supmat + (size_t)b * 1024 * 16;
    uint64_t pre[16];
    #pragma unroll
    for (int d = 0; d < 16; ++d) pre[d] = row[(size_t)d * 16 + w16];
    for (int base = 0; base < KSEL; base += 16) {
        #pragma unroll
        for (int d = 0; d < 16; ++d) {
            int i = base + d;
            uint64_t kw = __shfl(keep, i >> 6);          // uniform broadcast
            if (i < KSEL && ((kw >> (i & 63)) & 1ull))
                keep &= ~pre[d];
            pre[d] = row[(size_t)(base + 16 + d) * 16 + w16];  // rows padded to 1024
        }
    }
    const int keep_off = BATCH * KSEL * 4 + 2 * BATCH * KSEL;
    #pragma unroll
    for (int it = 0; it < 16; ++it) {
        int j = it * 64 + lane;
        uint64_t kw = __shfl(keep, it);
        if (j < KSEL)
            out[keep_off + b * KSEL + j] = ((kw >> lane) & 1ull) ? 1.0f : 0.0f;
    }
}

extern "C" void kernel_launch(void* const* d_in, const int* in_sizes, int n_in,
                              void* d_out, int out_size, void* d_ws, size_t ws_size,
                              hipStream_t stream) {
    const float* anchors        = (const float*)d_in[1];
    const float* regression     = (const float*)d_in[2];
    const float* classification = (const float*)d_in[3];
    float* out = (float*)d_out;

    char* ws = (char*)d_ws;
    const size_t BA = (size_t)BATCH * A_NUM;          // 392832
    float*    scores   = (float*)ws;                  // 1,571,328 B
    int*      classes  = (int*)(ws + 1571328);        // 1,571,328 B
    uint64_t* selkeys  = (uint64_t*)(ws + 3142656);   // 65,536 B
    uint64_t* kstar    = (uint64_t*)(ws + 3208192);   // 64 B
    int*      counters = (int*)(ws + 3208256);        // 32 B
    uint64_t* supmat   = (uint64_t*)(ws + 3211264);   // 8*1024*16*8 = 1,048,576 B
    uint64_t* validw   = (uint64_t*)(ws + 4259840);   // 1,024 B

    int nblk = (int)((BA + 255) / 256);
    score_kernel<<<nblk, 256, 0, stream>>>(classification, scores, classes);
    select_kernel<<<BATCH, 1024, 0, stream>>>(scores, kstar, counters, selkeys);
    compact_kernel<<<nblk, 256, 0, stream>>>(scores, kstar, counters, selkeys);
    sort_emit_kernel<<<BATCH, 1024, 0, stream>>>(selkeys, scores, classes, anchors,
                                                 regression, out, validw);
    supmat_kernel<<<dim3(63, BATCH), 256, 0, stream>>>(out, supmat);
    scan_kernel<<<BATCH, 64, 0, stream>>>(supmat, validw, out);
}

// Round 3
// 258.151 us; speedup vs baseline: 2.1262x; 1.2168x over previous
//
#include <hip/hip_runtime.h>
#include <stdint.h>

// EfficientDet post-process: score max/argmax -> top-1000 select -> sort -> NMS.
#define A_NUM   49104
#define BATCH   8
#define NCLS    90
#define KSEL    1000
#define SCORE_T 0.05f
#define IOU_T   0.5f
#define IMG_F   512.0f

#define HBLK    12          // histogram blocks per image
#define CHUNK   4092        // 12 * 4092 = 49104 exactly

// monotonic 32-bit transform: float compare == unsigned compare
__device__ __forceinline__ uint32_t mono32(float s) {
    uint32_t u = __float_as_uint(s);
    return (u & 0x80000000u) ? ~u : (u | 0x80000000u);
}
// unique 48-bit descending key: (mono score << 16) | (0xFFFF - anchor)
__device__ __forceinline__ uint64_t make_key(float s, int a) {
    return ((uint64_t)mono32(s) << 16) | (uint64_t)(0xFFFFu - (uint32_t)a);
}

// ---- kernel 1: per-anchor class max + argmax, mask <= T to -1
__global__ void score_kernel(const float* __restrict__ cls,
                             float* __restrict__ scores,
                             int* __restrict__ classes) {
    int i = blockIdx.x * blockDim.x + threadIdx.x;
    const int BA = BATCH * A_NUM;
    if (i >= BA) return;
    const float* row = cls + (size_t)i * NCLS;
    float best = -1e30f; int bc = 0;
    #pragma unroll 9
    for (int c = 0; c < NCLS; c += 2) {
        float2 v = *reinterpret_cast<const float2*>(row + c);
        if (v.x > best) { best = v.x; bc = c; }
        if (v.y > best) { best = v.y; bc = c + 1; }
    }
    scores[i]  = (best > SCORE_T) ? best : -1.0f;
    classes[i] = bc;
}

// ---- 16-bit histogram pass (PASS=1: bits[31:16], PASS=2: bits[15:0] within prefix)
// 128 KiB LDS packed-uint16 histogram -> sparse global atomic merge.
template<int PASS>
__global__ void __launch_bounds__(1024) hist_kernel(const float* __restrict__ scores,
                                                    const uint32_t* __restrict__ prefix1,
                                                    uint32_t* __restrict__ ghist) {
    __shared__ uint32_t lh[32768];
    const int b   = blockIdx.x / HBLK;
    const int c   = blockIdx.x % HBLK;
    const int tid = threadIdx.x;
    #pragma unroll
    for (int t = tid; t < 32768; t += 1024) lh[t] = 0;
    __syncthreads();
    const float* sc = scores + (size_t)b * A_NUM;
    const uint32_t pfx = (PASS == 2) ? prefix1[b] : 0;
    const int i0 = c * CHUNK;
    const int i1 = (i0 + CHUNK < A_NUM) ? i0 + CHUNK : A_NUM;
    for (int i = i0 + tid; i < i1; i += 1024) {
        uint32_t u = mono32(sc[i]);
        uint32_t bin; bool ok;
        if (PASS == 1) { bin = u >> 16;      ok = true; }
        else           { bin = u & 0xFFFFu;  ok = ((u >> 16) == pfx); }
        if (ok) atomicAdd(&lh[bin >> 1], (bin & 1) ? 0x10000u : 1u);
    }
    __syncthreads();
    uint32_t* gh = ghist + (size_t)b * 65536;
    for (int t = tid; t < 32768; t += 1024) {
        uint32_t v = lh[t];
        if (v) {
            uint32_t lo = v & 0xFFFFu, hi = v >> 16;
            if (lo) atomicAdd(&gh[2 * t],     lo);
            if (hi) atomicAdd(&gh[2 * t + 1], hi);
        }
    }
}

// ---- boundary-bin scan over 65536 bins, 1 block/image.
// PASS=1: out prefix bin + residual target. PASS=2: out exact 32-bit threshold;
// also zero-init selkeys (1024 slots) and counters for compact.
template<int PASS>
__global__ void __launch_bounds__(1024) hscan_kernel(const uint32_t* __restrict__ ghist,
                                                     const uint32_t* __restrict__ target_in,
                                                     const uint32_t* __restrict__ prefix_in,
                                                     uint32_t* __restrict__ out0,   // bin | thr32
                                                     uint32_t* __restrict__ out1,   // target2
                                                     uint64_t* __restrict__ selkeys,
                                                     int* __restrict__ counters) {
    __shared__ uint32_t ssum[1024];
    const int b   = blockIdx.x;
    const int tid = threadIdx.x;
    const uint32_t target = (PASS == 1) ? (uint32_t)KSEL : target_in[b];
    uint32_t loc[64];
    const uint4* h4 = reinterpret_cast<const uint4*>(ghist + (size_t)b * 65536 + tid * 64);
    #pragma unroll
    for (int k = 0; k < 16; ++k) {
        uint4 v = h4[k];
        loc[4 * k] = v.x; loc[4 * k + 1] = v.y; loc[4 * k + 2] = v.z; loc[4 * k + 3] = v.w;
    }
    uint32_t mysum = 0;
    #pragma unroll
    for (int k = 0; k < 64; ++k) mysum += loc[k];
    ssum[tid] = mysum;
    __syncthreads();
    for (int off = 1; off < 1024; off <<= 1) {
        uint32_t v = ssum[tid];
        if (tid + off < 1024) v += ssum[tid + off];
        __syncthreads();
        ssum[tid] = v;
        __syncthreads();
    }
    uint32_t acc = ssum[tid] - mysum;        // count strictly above my bin range
    #pragma unroll
    for (int k = 63; k >= 0; --k) {
        uint32_t na = acc + loc[k];
        if (na >= target && acc < target) {  // unique crossing
            uint32_t bin = (uint32_t)(tid * 64 + k);
            if (PASS == 1) { out0[b] = bin; out1[b] = target - acc; }
            else           { out0[b] = (prefix_in[b] << 16) | bin; }
        }
        acc = na;
    }
    if (PASS == 2) {
        selkeys[b * 1024 + tid] = 0;
        if (tid == 0) counters[b] = 0;
    }
}

// ---- compact: all keys with score-bits >= thr32 (1000 + exact-score ties, <=1024 whp)
__global__ void compact_kernel(const float* __restrict__ scores,
                               const uint32_t* __restrict__ thr32,
                               int* __restrict__ counters,
                               uint64_t* __restrict__ selkeys) {
    int i = blockIdx.x * blockDim.x + threadIdx.x;
    const int BA = BATCH * A_NUM;
    if (i >= BA) return;
    int b = i / A_NUM;
    int a = i - b * A_NUM;
    uint32_t u = mono32(scores[i]);
    if (u >= thr32[b]) {
        int pos = atomicAdd(&counters[b], 1);
        if (pos < 1024) selkeys[b * 1024 + pos] = ((uint64_t)u << 16) | (uint64_t)(0xFFFFu - (uint32_t)a);
    }
}

// ---- bitonic sort 1024 keys descending (full 48-bit key -> exact top_k order);
// decode + emit boxes/scores/labels; valid bitmask
__global__ void __launch_bounds__(1024) sort_emit_kernel(const uint64_t* __restrict__ selkeys,
                                                         const float* __restrict__ scores,
                                                         const int* __restrict__ classes,
                                                         const float* __restrict__ anchors,
                                                         const float* __restrict__ regression,
                                                         float* __restrict__ out,
                                                         uint64_t* __restrict__ validw) {
    __shared__ uint64_t keys[1024];
    const int b   = blockIdx.x;
    const int tid = threadIdx.x;
    keys[tid] = selkeys[b * 1024 + tid];
    __syncthreads();
    for (int k = 2; k <= 1024; k <<= 1) {
        for (int j = k >> 1; j > 0; j >>= 1) {
            int partner = tid ^ j;
            if (partner > tid) {
                uint64_t a0 = keys[tid], a1 = keys[partner];
                bool up = ((tid & k) == 0);
                bool sw = up ? (a0 < a1) : (a0 > a1);
                if (sw) { keys[tid] = a1; keys[partner] = a0; }
            }
            __syncthreads();
        }
    }
    float sval = -1.0f;
    if (tid < KSEL) {
        uint64_t key = keys[tid];
        int a = 0xFFFF - (int)(key & 0xFFFFu);
        size_t gi = (size_t)b * A_NUM + a;
        float s = scores[gi];
        int   c = classes[gi];
        const float* an = anchors + (size_t)a * 4;
        const float* rg = regression + gi * 4;
        float y1a = an[0], x1a = an[1], y2a = an[2], x2a = an[3];
        float ya = (y1a + y2a) * 0.5f, xa = (x1a + x2a) * 0.5f;
        float ha = y2a - y1a,          wa = x2a - x1a;
        float r0 = rg[0], r1 = rg[1], r2 = rg[2], r3 = rg[3];
        float w  = expf(r3) * wa;
        float h  = expf(r2) * ha;
        float yc = r0 * ha + ya;
        float xc = r1 * wa + xa;
        float x1 = fmaxf(xc - w * 0.5f, 0.0f);
        float y1 = fmaxf(yc - h * 0.5f, 0.0f);
        float x2 = fminf(xc + w * 0.5f, IMG_F);
        float y2 = fminf(yc + h * 0.5f, IMG_F);
        int o = b * KSEL + tid;
        out[(size_t)o * 4 + 0] = x1;
        out[(size_t)o * 4 + 1] = y1;
        out[(size_t)o * 4 + 2] = x2;
        out[(size_t)o * 4 + 3] = y2;
        out[BATCH * KSEL * 4 + o]                = s;
        out[BATCH * KSEL * 4 + BATCH * KSEL + o] = (float)(c + 1);
        sval = s;
    }
    unsigned long long vm = __ballot(sval > SCORE_T);
    if ((tid & 63) == 0) validw[b * 16 + (tid >> 6)] = vm;
}

// ---- suppression bitmask matrix: sup[b][i][w] over j-word w (j>i, same class, iou>T)
__global__ void __launch_bounds__(256) supmat_kernel(const float* __restrict__ out,
                                                     uint64_t* __restrict__ supmat) {
    __shared__ float4 sbox[KSEL];
    __shared__ float  sarea[KSEL];
    __shared__ int    scls[KSEL];
    const int g    = blockIdx.x;       // 0..62 (16 i's each)
    const int b    = blockIdx.y;
    const int tid  = threadIdx.x;
    const int lane = tid & 63;
    const int wv   = tid >> 6;
    const int label_off = BATCH * KSEL * 4 + BATCH * KSEL;
    for (int j = tid; j < KSEL; j += 256) {
        float4 v = *reinterpret_cast<const float4*>(out + (size_t)(b * KSEL + j) * 4);
        sbox[j]  = v;
        sarea[j] = (v.z - v.x) * (v.w - v.y);
        scls[j]  = (int)out[label_off + b * KSEL + j];
    }
    __syncthreads();
    #pragma unroll
    for (int q = 0; q < 4; ++q) {
        int i = g * 16 + wv * 4 + q;
        if (i >= KSEL) continue;                 // wave-uniform
        float4 bi = sbox[i];
        float  ai = sarea[i];
        int    ci = scls[i];
        uint64_t* dst = supmat + ((size_t)b * 1024 + i) * 16;
        #pragma unroll
        for (int w = 0; w < 16; ++w) {
            int j = w * 64 + lane;
            bool sup = false;
            if (j > i && j < KSEL) {
                float4 bj = sbox[j];
                float lx = fmaxf(bi.x, bj.x), ly = fmaxf(bi.y, bj.y);
                float rx = fminf(bi.z, bj.z), ry = fminf(bi.w, bj.w);
                float iw = fmaxf(rx - lx, 0.0f), ih = fmaxf(ry - ly, 0.0f);
                float inter = iw * ih;
                float iou = inter / (ai + sarea[j] - inter + 1e-8f);
                sup = (iou > IOU_T) && (ci == scls[j]);
            }
            unsigned long long m = __ballot(sup);
            if (lane == 0) dst[w] = m;
        }
    }
}

// ---- serial greedy scan, one wave per image, no barriers
__global__ void __launch_bounds__(64) nms_scan_kernel(const uint64_t* __restrict__ supmat,
                                                      const uint64_t* __restrict__ validw,
                                                      float* __restrict__ out) {
    const int b    = blockIdx.x;
    const int lane = threadIdx.x;
    const int w16  = lane & 15;
    uint64_t keep = validw[b * 16 + w16];
    const uint64_t* row = supmat + (size_t)b * 1024 * 16;
    uint64_t pre[16];
    #pragma unroll
    for (int d = 0; d < 16; ++d) pre[d] = row[(size_t)d * 16 + w16];
    for (int base = 0; base < KSEL; base += 16) {
        #pragma unroll
        for (int d = 0; d < 16; ++d) {
            int i = base + d;
            uint64_t kw = __shfl(keep, i >> 6);
            if (i < KSEL && ((kw >> (i & 63)) & 1ull))
                keep &= ~pre[d];
            pre[d] = row[(size_t)(base + 16 + d) * 16 + w16];
        }
    }
    const int keep_off = BATCH * KSEL * 4 + 2 * BATCH * KSEL;
    #pragma unroll
    for (int it = 0; it < 16; ++it) {
        int j = it * 64 + lane;
        uint64_t kw = __shfl(keep, it);
        if (j < KSEL)
            out[keep_off + b * KSEL + j] = ((kw >> lane) & 1ull) ? 1.0f : 0.0f;
    }
}

extern "C" void kernel_launch(void* const* d_in, const int* in_sizes, int n_in,
                              void* d_out, int out_size, void* d_ws, size_t ws_size,
                              hipStream_t stream) {
    const float* anchors        = (const float*)d_in[1];
    const float* regression     = (const float*)d_in[2];
    const float* classification = (const float*)d_in[3];
    float* out = (float*)d_out;

    char* ws = (char*)d_ws;
    const size_t BA = (size_t)BATCH * A_NUM;          // 392832
    float*    scores   = (float*)ws;                  // 1,571,328 B
    int*      classes  = (int*)(ws + 1571328);        // 1,571,328 B
    uint64_t* selkeys  = (uint64_t*)(ws + 3142656);   // 65,536 B
    uint32_t* prefix1  = (uint32_t*)(ws + 3208192);   // 32 B
    uint32_t* target2  = (uint32_t*)(ws + 3208448);   // 32 B
    uint32_t* thr32    = (uint32_t*)(ws + 3208704);   // 32 B
    int*      counters = (int*)(ws + 3208960);        // 32 B
    uint64_t* validw   = (uint64_t*)(ws + 3209216);   // 1,024 B
    uint64_t* supmat   = (uint64_t*)(ws + 3211264);   // 1,048,576 B (ends 4,259,840)
    uint32_t* ghist1   = (uint32_t*)(ws + 4259840);   // 2,097,152 B
    uint32_t* ghist2   = (uint32_t*)(ws + 6356992);   // 2,097,152 B (ends 8,454,144)

    hipMemsetAsync(ghist1, 0, 2 * 2097152, stream);   // both histograms

    int nblk = (int)((BA + 255) / 256);
    score_kernel<<<nblk, 256, 0, stream>>>(classification, scores, classes);
    hist_kernel<1><<<BATCH * HBLK, 1024, 0, stream>>>(scores, nullptr, ghist1);
    hscan_kernel<1><<<BATCH, 1024, 0, stream>>>(ghist1, nullptr, nullptr,
                                                prefix1, target2, nullptr, nullptr);
    hist_kernel<2><<<BATCH * HBLK, 1024, 0, stream>>>(scores, prefix1, ghist2);
    hscan_kernel<2><<<BATCH, 1024, 0, stream>>>(ghist2, target2, prefix1,
                                                thr32, nullptr, selkeys, counters);
    compact_kernel<<<nblk, 256, 0, stream>>>(scores, thr32, counters, selkeys);
    sort_emit_kernel<<<BATCH, 1024, 0, stream>>>(selkeys, scores, classes, anchors,
                                                 regression, out, validw);
    supmat_kernel<<<dim3(63, BATCH), 256, 0, stream>>>(out, supmat);
    nms_scan_kernel<<<BATCH, 64, 0, stream>>>(supmat, validw, out);
}

// Round 4
// 167.634 us; speedup vs baseline: 3.2743x; 1.5400x over previous
//
#include <hip/hip_runtime.h>
#include <stdint.h>

// EfficientDet post-process: score max/argmax -> top-1000 select -> sort -> NMS.
#define A_NUM   49104
#define BATCH   8
#define NCLS    90
#define KSEL    1000
#define SCORE_T 0.05f
#define IOU_T   0.5f
#define IMG_F   512.0f

#define HBLK    12          // histogram blocks per image
#define CHUNK   4092        // 12 * 4092 = 49104 exactly

// monotonic 32-bit transform: float compare == unsigned compare
__device__ __forceinline__ uint32_t mono32(float s) {
    uint32_t u = __float_as_uint(s);
    return (u & 0x80000000u) ? ~u : (u | 0x80000000u);
}

// ---- kernel 1: per-anchor class max + argmax, mask <= T to -1
__global__ void score_kernel(const float* __restrict__ cls,
                             float* __restrict__ scores,
                             int* __restrict__ classes) {
    int i = blockIdx.x * blockDim.x + threadIdx.x;
    const int BA = BATCH * A_NUM;
    if (i >= BA) return;
    const float* row = cls + (size_t)i * NCLS;
    float best = -1e30f; int bc = 0;
    #pragma unroll 9
    for (int c = 0; c < NCLS; c += 2) {
        float2 v = *reinterpret_cast<const float2*>(row + c);
        if (v.x > best) { best = v.x; bc = c; }
        if (v.y > best) { best = v.y; bc = c + 1; }
    }
    scores[i]  = (best > SCORE_T) ? best : -1.0f;
    classes[i] = bc;
}

// ---- 16-bit histogram pass (PASS=1: bits[31:16], PASS=2: bits[15:0] within prefix)
// 128 KiB LDS packed-uint16 histogram -> sparse global atomic merge.
template<int PASS>
__global__ void __launch_bounds__(1024) hist_kernel(const float* __restrict__ scores,
                                                    const uint32_t* __restrict__ prefix1,
                                                    uint32_t* __restrict__ ghist) {
    __shared__ uint32_t lh[32768];
    const int b   = blockIdx.x / HBLK;
    const int c   = blockIdx.x % HBLK;
    const int tid = threadIdx.x;
    #pragma unroll
    for (int t = tid; t < 32768; t += 1024) lh[t] = 0;
    __syncthreads();
    const float* sc = scores + (size_t)b * A_NUM;
    const uint32_t pfx = (PASS == 2) ? prefix1[b] : 0;
    const int i0 = c * CHUNK;
    const int i1 = (i0 + CHUNK < A_NUM) ? i0 + CHUNK : A_NUM;
    for (int i = i0 + tid; i < i1; i += 1024) {
        uint32_t u = mono32(sc[i]);
        uint32_t bin; bool ok;
        if (PASS == 1) { bin = u >> 16;      ok = true; }
        else           { bin = u & 0xFFFFu;  ok = ((u >> 16) == pfx); }
        if (ok) atomicAdd(&lh[bin >> 1], (bin & 1) ? 0x10000u : 1u);
    }
    __syncthreads();
    uint32_t* gh = ghist + (size_t)b * 65536;
    for (int t = tid; t < 32768; t += 1024) {
        uint32_t v = lh[t];
        if (v) {
            uint32_t lo = v & 0xFFFFu, hi = v >> 16;
            if (lo) atomicAdd(&gh[2 * t],     lo);
            if (hi) atomicAdd(&gh[2 * t + 1], hi);
        }
    }
}

// ---- boundary-bin scan over 65536 bins, 1 block/image.
// PASS=1: out prefix bin + residual target. PASS=2: out exact 32-bit threshold;
// also zero-init selkeys (1024 slots) and padded counters for compact.
template<int PASS>
__global__ void __launch_bounds__(1024) hscan_kernel(const uint32_t* __restrict__ ghist,
                                                     const uint32_t* __restrict__ target_in,
                                                     const uint32_t* __restrict__ prefix_in,
                                                     uint32_t* __restrict__ out0,   // bin | thr32
                                                     uint32_t* __restrict__ out1,   // target2
                                                     uint64_t* __restrict__ selkeys,
                                                     int* __restrict__ counters) {
    __shared__ uint32_t ssum[1024];
    const int b   = blockIdx.x;
    const int tid = threadIdx.x;
    const uint32_t target = (PASS == 1) ? (uint32_t)KSEL : target_in[b];
    uint32_t loc[64];
    const uint4* h4 = reinterpret_cast<const uint4*>(ghist + (size_t)b * 65536 + tid * 64);
    #pragma unroll
    for (int k = 0; k < 16; ++k) {
        uint4 v = h4[k];
        loc[4 * k] = v.x; loc[4 * k + 1] = v.y; loc[4 * k + 2] = v.z; loc[4 * k + 3] = v.w;
    }
    uint32_t mysum = 0;
    #pragma unroll
    for (int k = 0; k < 64; ++k) mysum += loc[k];
    ssum[tid] = mysum;
    __syncthreads();
    for (int off = 1; off < 1024; off <<= 1) {
        uint32_t v = ssum[tid];
        if (tid + off < 1024) v += ssum[tid + off];
        __syncthreads();
        ssum[tid] = v;
        __syncthreads();
    }
    uint32_t acc = ssum[tid] - mysum;        // count strictly above my bin range
    #pragma unroll
    for (int k = 63; k >= 0; --k) {
        uint32_t na = acc + loc[k];
        if (na >= target && acc < target) {  // unique crossing
            uint32_t bin = (uint32_t)(tid * 64 + k);
            if (PASS == 1) { out0[b] = bin; out1[b] = target - acc; }
            else           { out0[b] = (prefix_in[b] << 16) | bin; }
        }
        acc = na;
    }
    if (PASS == 2) {
        selkeys[b * 1024 + tid] = 0;
        if (tid == 0) counters[b * 64] = 0;
    }
}

// ---- compact: all keys with score-bits >= thr32 (1000 + exact-score ties).
// Block-aggregated atomic (48/image) to line-padded counters: no atomic convoy.
__global__ void __launch_bounds__(1024) compact_kernel(const float* __restrict__ scores,
                                                       const uint32_t* __restrict__ thr32,
                                                       int* __restrict__ counters,
                                                       uint64_t* __restrict__ selkeys) {
    __shared__ int wbase[16];
    __shared__ int sbase;
    const int b    = blockIdx.y;
    const int tid  = threadIdx.x;
    const int i    = blockIdx.x * 1024 + tid;
    const int lane = tid & 63, wid = tid >> 6;
    bool pass = false; uint32_t u = 0;
    if (i < A_NUM) {
        u = mono32(scores[(size_t)b * A_NUM + i]);
        pass = (u >= thr32[b]);
    }
    uint64_t m = __ballot(pass);
    if (lane == 0) wbase[wid] = __popcll(m);
    __syncthreads();
    if (tid == 0) {
        int tot = 0;
        #pragma unroll
        for (int w = 0; w < 16; ++w) { int c = wbase[w]; wbase[w] = tot; tot += c; }
        sbase = tot ? atomicAdd(&counters[b * 64], tot) : 0;
    }
    __syncthreads();
    if (pass) {
        int pos = sbase + wbase[wid] + __popcll(m & ((1ull << lane) - 1ull));
        if (pos < 1024)
            selkeys[b * 1024 + pos] =
                ((uint64_t)u << 16) | (uint64_t)(0xFFFFu - (uint32_t)i);
    }
}

// ---- bitonic sort 1024 keys descending (full 48-bit key -> exact top_k order);
// decode + emit boxes/scores/labels; valid bitmask
__global__ void __launch_bounds__(1024) sort_emit_kernel(const uint64_t* __restrict__ selkeys,
                                                         const float* __restrict__ scores,
                                                         const int* __restrict__ classes,
                                                         const float* __restrict__ anchors,
                                                         const float* __restrict__ regression,
                                                         float* __restrict__ out,
                                                         uint64_t* __restrict__ validw) {
    __shared__ uint64_t keys[1024];
    const int b   = blockIdx.x;
    const int tid = threadIdx.x;
    keys[tid] = selkeys[b * 1024 + tid];
    __syncthreads();
    for (int k = 2; k <= 1024; k <<= 1) {
        for (int j = k >> 1; j > 0; j >>= 1) {
            int partner = tid ^ j;
            if (partner > tid) {
                uint64_t a0 = keys[tid], a1 = keys[partner];
                bool up = ((tid & k) == 0);
                bool sw = up ? (a0 < a1) : (a0 > a1);
                if (sw) { keys[tid] = a1; keys[partner] = a0; }
            }
            __syncthreads();
        }
    }
    float sval = -1.0f;
    if (tid < KSEL) {
        uint64_t key = keys[tid];
        int a = 0xFFFF - (int)(key & 0xFFFFu);
        size_t gi = (size_t)b * A_NUM + a;
        float s = scores[gi];
        int   c = classes[gi];
        const float* an = anchors + (size_t)a * 4;
        const float* rg = regression + gi * 4;
        float y1a = an[0], x1a = an[1], y2a = an[2], x2a = an[3];
        float ya = (y1a + y2a) * 0.5f, xa = (x1a + x2a) * 0.5f;
        float ha = y2a - y1a,          wa = x2a - x1a;
        float r0 = rg[0], r1 = rg[1], r2 = rg[2], r3 = rg[3];
        float w  = expf(r3) * wa;
        float h  = expf(r2) * ha;
        float yc = r0 * ha + ya;
        float xc = r1 * wa + xa;
        float x1 = fmaxf(xc - w * 0.5f, 0.0f);
        float y1 = fmaxf(yc - h * 0.5f, 0.0f);
        float x2 = fminf(xc + w * 0.5f, IMG_F);
        float y2 = fminf(yc + h * 0.5f, IMG_F);
        int o = b * KSEL + tid;
        out[(size_t)o * 4 + 0] = x1;
        out[(size_t)o * 4 + 1] = y1;
        out[(size_t)o * 4 + 2] = x2;
        out[(size_t)o * 4 + 3] = y2;
        out[BATCH * KSEL * 4 + o]                = s;
        out[BATCH * KSEL * 4 + BATCH * KSEL + o] = (float)(c + 1);
        sval = s;
    }
    unsigned long long vm = __ballot(sval > SCORE_T);
    if ((tid & 63) == 0) validw[b * 16 + (tid >> 6)] = vm;
}

// ---- suppression bitmask matrix: sup[b][i][w] over j-word w (j>i, same class, iou>T)
__global__ void __launch_bounds__(256) supmat_kernel(const float* __restrict__ out,
                                                     uint64_t* __restrict__ supmat) {
    __shared__ float4 sbox[KSEL];
    __shared__ float  sarea[KSEL];
    __shared__ int    scls[KSEL];
    const int g    = blockIdx.x;       // 0..62 (16 i's each)
    const int b    = blockIdx.y;
    const int tid  = threadIdx.x;
    const int lane = tid & 63;
    const int wv   = tid >> 6;
    const int label_off = BATCH * KSEL * 4 + BATCH * KSEL;
    for (int j = tid; j < KSEL; j += 256) {
        float4 v = *reinterpret_cast<const float4*>(out + (size_t)(b * KSEL + j) * 4);
        sbox[j]  = v;
        sarea[j] = (v.z - v.x) * (v.w - v.y);
        scls[j]  = (int)out[label_off + b * KSEL + j];
    }
    __syncthreads();
    #pragma unroll
    for (int q = 0; q < 4; ++q) {
        int i = g * 16 + wv * 4 + q;
        if (i >= KSEL) continue;                 // wave-uniform
        float4 bi = sbox[i];
        float  ai = sarea[i];
        int    ci = scls[i];
        uint64_t* dst = supmat + ((size_t)b * 1024 + i) * 16;
        #pragma unroll
        for (int w = 0; w < 16; ++w) {
            int j = w * 64 + lane;
            bool sup = false;
            if (j > i && j < KSEL) {
                float4 bj = sbox[j];
                float lx = fmaxf(bi.x, bj.x), ly = fmaxf(bi.y, bj.y);
                float rx = fminf(bi.z, bj.z), ry = fminf(bi.w, bj.w);
                float iw = fmaxf(rx - lx, 0.0f), ih = fmaxf(ry - ly, 0.0f);
                float inter = iw * ih;
                float iou = inter / (ai + sarea[j] - inter + 1e-8f);
                sup = (iou > IOU_T) && (ci == scls[j]);
            }
            unsigned long long m = __ballot(sup);
            if (lane == 0) dst[w] = m;
        }
    }
}

// ---- serial greedy scan, one wave per image, no barriers
__global__ void __launch_bounds__(64) nms_scan_kernel(const uint64_t* __restrict__ supmat,
                                                      const uint64_t* __restrict__ validw,
                                                      float* __restrict__ out) {
    const int b    = blockIdx.x;
    const int lane = threadIdx.x;
    const int w16  = lane & 15;
    uint64_t keep = validw[b * 16 + w16];
    const uint64_t* row = supmat + (size_t)b * 1024 * 16;
    uint64_t pre[16];
    #pragma unroll
    for (int d = 0; d < 16; ++d) pre[d] = row[(size_t)d * 16 + w16];
    for (int base = 0; base < KSEL; base += 16) {
        #pragma unroll
        for (int d = 0; d < 16; ++d) {
            int i = base + d;
            uint64_t kw = __shfl(keep, i >> 6);
            if (i < KSEL && ((kw >> (i & 63)) & 1ull))
                keep &= ~pre[d];
            pre[d] = row[(size_t)(base + 16 + d) * 16 + w16];
        }
    }
    const int keep_off = BATCH * KSEL * 4 + 2 * BATCH * KSEL;
    #pragma unroll
    for (int it = 0; it < 16; ++it) {
        int j = it * 64 + lane;
        uint64_t kw = __shfl(keep, it);
        if (j < KSEL)
            out[keep_off + b * KSEL + j] = ((kw >> lane) & 1ull) ? 1.0f : 0.0f;
    }
}

extern "C" void kernel_launch(void* const* d_in, const int* in_sizes, int n_in,
                              void* d_out, int out_size, void* d_ws, size_t ws_size,
                              hipStream_t stream) {
    const float* anchors        = (const float*)d_in[1];
    const float* regression     = (const float*)d_in[2];
    const float* classification = (const float*)d_in[3];
    float* out = (float*)d_out;

    char* ws = (char*)d_ws;
    const size_t BA = (size_t)BATCH * A_NUM;          // 392832
    float*    scores   = (float*)ws;                  // 1,571,328 B
    int*      classes  = (int*)(ws + 1571328);        // 1,571,328 B -> 3,142,656
    uint64_t* selkeys  = (uint64_t*)(ws + 3142656);   // 65,536 B   -> 3,208,192
    uint32_t* prefix1  = (uint32_t*)(ws + 3208192);   // 256 B
    uint32_t* target2  = (uint32_t*)(ws + 3208448);   // 256 B
    uint32_t* thr32    = (uint32_t*)(ws + 3208704);   // 256 B
    int*      counters = (int*)(ws + 3208960);        // 2,048 B (8 x 256B lines)
    uint64_t* validw   = (uint64_t*)(ws + 3211008);   // 1,024 B  -> 3,212,032
    uint64_t* supmat   = (uint64_t*)(ws + 3212032);   // 1,048,576 B -> 4,260,608
    uint32_t* ghist    = (uint32_t*)(ws + 4260608);   // 2,097,152 B -> 6,357,760

    int nblk = (int)((BA + 255) / 256);
    score_kernel<<<nblk, 256, 0, stream>>>(classification, scores, classes);
    hipMemsetAsync(ghist, 0, 2097152, stream);
    hist_kernel<1><<<BATCH * HBLK, 1024, 0, stream>>>(scores, nullptr, ghist);
    hscan_kernel<1><<<BATCH, 1024, 0, stream>>>(ghist, nullptr, nullptr,
                                                prefix1, target2, nullptr, nullptr);
    hipMemsetAsync(ghist, 0, 2097152, stream);
    hist_kernel<2><<<BATCH * HBLK, 1024, 0, stream>>>(scores, prefix1, ghist);
    hscan_kernel<2><<<BATCH, 1024, 0, stream>>>(ghist, target2, prefix1,
                                                thr32, nullptr, selkeys, counters);
    compact_kernel<<<dim3(48, BATCH), 1024, 0, stream>>>(scores, thr32, counters, selkeys);
    sort_emit_kernel<<<BATCH, 1024, 0, stream>>>(selkeys, scores, classes, anchors,
                                                 regression, out, validw);
    supmat_kernel<<<dim3(63, BATCH), 256, 0, stream>>>(out, supmat);
    nms_scan_kernel<<<BATCH, 64, 0, stream>>>(supmat, validw, out);
}

// Round 5
// 163.257 us; speedup vs baseline: 3.3621x; 1.0268x over previous
//
#include <hip/hip_runtime.h>
#include <stdint.h>

// EfficientDet post-process: score max/argmax -> top-1000 select -> sort -> NMS.
#define A_NUM   49104
#define BATCH   8
#define NCLS    90
#define KSEL    1000
#define SCORE_T 0.05f
#define IOU_T   0.5f
#define IMG_F   512.0f

#define HBLK    12          // histogram blocks per image
#define CHUNK   4092        // 12 * 4092 = 49104 exactly

// monotonic 32-bit transform: float compare == unsigned compare
__device__ __forceinline__ uint32_t mono32(float s) {
    uint32_t u = __float_as_uint(s);
    return (u & 0x80000000u) ? ~u : (u | 0x80000000u);
}

// ---- kernel 1: per-anchor class max + argmax, mask <= T to -1.
// Also zeroes both 2-MB global histograms (4 MB = 262144 uint4) -- replaces
// hipMemsetAsync, whose rocclr fill kernel ran at ~25 GB/s on the replay path.
__global__ void score_kernel(const float* __restrict__ cls,
                             float* __restrict__ scores,
                             int* __restrict__ classes,
                             uint4* __restrict__ ghist_zero) {
    int i = blockIdx.x * blockDim.x + threadIdx.x;
    if (i < 262144) ghist_zero[i] = uint4{0, 0, 0, 0};
    const int BA = BATCH * A_NUM;
    if (i >= BA) return;
    const float* row = cls + (size_t)i * NCLS;
    float best = -1e30f; int bc = 0;
    #pragma unroll 9
    for (int c = 0; c < NCLS; c += 2) {
        float2 v = *reinterpret_cast<const float2*>(row + c);
        if (v.x > best) { best = v.x; bc = c; }
        if (v.y > best) { best = v.y; bc = c + 1; }
    }
    scores[i]  = (best > SCORE_T) ? best : -1.0f;
    classes[i] = bc;
}

// ---- 16-bit histogram pass (PASS=1: bits[31:16], PASS=2: bits[15:0] within prefix)
// 128 KiB LDS packed-uint16 histogram -> sparse global atomic merge.
template<int PASS>
__global__ void __launch_bounds__(1024) hist_kernel(const float* __restrict__ scores,
                                                    const uint32_t* __restrict__ prefix1,
                                                    uint32_t* __restrict__ ghist) {
    __shared__ uint32_t lh[32768];
    const int b   = blockIdx.x / HBLK;
    const int c   = blockIdx.x % HBLK;
    const int tid = threadIdx.x;
    #pragma unroll
    for (int t = tid; t < 32768; t += 1024) lh[t] = 0;
    __syncthreads();
    const float* sc = scores + (size_t)b * A_NUM;
    const uint32_t pfx = (PASS == 2) ? prefix1[b] : 0;
    const int i0 = c * CHUNK;
    const int i1 = (i0 + CHUNK < A_NUM) ? i0 + CHUNK : A_NUM;
    for (int i = i0 + tid; i < i1; i += 1024) {
        uint32_t u = mono32(sc[i]);
        uint32_t bin; bool ok;
        if (PASS == 1) { bin = u >> 16;      ok = true; }
        else           { bin = u & 0xFFFFu;  ok = ((u >> 16) == pfx); }
        if (ok) atomicAdd(&lh[bin >> 1], (bin & 1) ? 0x10000u : 1u);
    }
    __syncthreads();
    uint32_t* gh = ghist + (size_t)b * 65536;
    for (int t = tid; t < 32768; t += 1024) {
        uint32_t v = lh[t];
        if (v) {
            uint32_t lo = v & 0xFFFFu, hi = v >> 16;
            if (lo) atomicAdd(&gh[2 * t],     lo);
            if (hi) atomicAdd(&gh[2 * t + 1], hi);
        }
    }
}

// ---- boundary-bin scan over 65536 bins, 1 block/image.
// PASS=1: out prefix bin + residual target. PASS=2: out exact 32-bit threshold;
// also zero-init selkeys (1024 slots) and padded counters for compact.
template<int PASS>
__global__ void __launch_bounds__(1024) hscan_kernel(const uint32_t* __restrict__ ghist,
                                                     const uint32_t* __restrict__ target_in,
                                                     const uint32_t* __restrict__ prefix_in,
                                                     uint32_t* __restrict__ out0,   // bin | thr32
                                                     uint32_t* __restrict__ out1,   // target2
                                                     uint64_t* __restrict__ selkeys,
                                                     int* __restrict__ counters) {
    __shared__ uint32_t ssum[1024];
    const int b   = blockIdx.x;
    const int tid = threadIdx.x;
    const uint32_t target = (PASS == 1) ? (uint32_t)KSEL : target_in[b];
    uint32_t loc[64];
    const uint4* h4 = reinterpret_cast<const uint4*>(ghist + (size_t)b * 65536 + tid * 64);
    #pragma unroll
    for (int k = 0; k < 16; ++k) {
        uint4 v = h4[k];
        loc[4 * k] = v.x; loc[4 * k + 1] = v.y; loc[4 * k + 2] = v.z; loc[4 * k + 3] = v.w;
    }
    uint32_t mysum = 0;
    #pragma unroll
    for (int k = 0; k < 64; ++k) mysum += loc[k];
    ssum[tid] = mysum;
    __syncthreads();
    for (int off = 1; off < 1024; off <<= 1) {
        uint32_t v = ssum[tid];
        if (tid + off < 1024) v += ssum[tid + off];
        __syncthreads();
        ssum[tid] = v;
        __syncthreads();
    }
    uint32_t acc = ssum[tid] - mysum;        // count strictly above my bin range
    #pragma unroll
    for (int k = 63; k >= 0; --k) {
        uint32_t na = acc + loc[k];
        if (na >= target && acc < target) {  // unique crossing
            uint32_t bin = (uint32_t)(tid * 64 + k);
            if (PASS == 1) { out0[b] = bin; out1[b] = target - acc; }
            else           { out0[b] = (prefix_in[b] << 16) | bin; }
        }
        acc = na;
    }
    if (PASS == 2) {
        selkeys[b * 1024 + tid] = 0;
        if (tid == 0) counters[b * 64] = 0;
    }
}

// ---- compact: all keys with score-bits >= thr32 (1000 + exact-score ties).
// Block-aggregated atomic (48/image) to line-padded counters: no atomic convoy.
__global__ void __launch_bounds__(1024) compact_kernel(const float* __restrict__ scores,
                                                       const uint32_t* __restrict__ thr32,
                                                       int* __restrict__ counters,
                                                       uint64_t* __restrict__ selkeys) {
    __shared__ int wbase[16];
    __shared__ int sbase;
    const int b    = blockIdx.y;
    const int tid  = threadIdx.x;
    const int i    = blockIdx.x * 1024 + tid;
    const int lane = tid & 63, wid = tid >> 6;
    bool pass = false; uint32_t u = 0;
    if (i < A_NUM) {
        u = mono32(scores[(size_t)b * A_NUM + i]);
        pass = (u >= thr32[b]);
    }
    uint64_t m = __ballot(pass);
    if (lane == 0) wbase[wid] = __popcll(m);
    __syncthreads();
    if (tid == 0) {
        int tot = 0;
        #pragma unroll
        for (int w = 0; w < 16; ++w) { int c = wbase[w]; wbase[w] = tot; tot += c; }
        sbase = tot ? atomicAdd(&counters[b * 64], tot) : 0;
    }
    __syncthreads();
    if (pass) {
        int pos = sbase + wbase[wid] + __popcll(m & ((1ull << lane) - 1ull));
        if (pos < 1024)
            selkeys[b * 1024 + pos] =
                ((uint64_t)u << 16) | (uint64_t)(0xFFFFu - (uint32_t)i);
    }
}

// ---- bitonic sort 1024 keys descending (full 48-bit key -> exact top_k order);
// decode + emit boxes/scores/labels; valid bitmask
__global__ void __launch_bounds__(1024) sort_emit_kernel(const uint64_t* __restrict__ selkeys,
                                                         const float* __restrict__ scores,
                                                         const int* __restrict__ classes,
                                                         const float* __restrict__ anchors,
                                                         const float* __restrict__ regression,
                                                         float* __restrict__ out,
                                                         uint64_t* __restrict__ validw) {
    __shared__ uint64_t keys[1024];
    const int b   = blockIdx.x;
    const int tid = threadIdx.x;
    keys[tid] = selkeys[b * 1024 + tid];
    __syncthreads();
    for (int k = 2; k <= 1024; k <<= 1) {
        for (int j = k >> 1; j > 0; j >>= 1) {
            int partner = tid ^ j;
            if (partner > tid) {
                uint64_t a0 = keys[tid], a1 = keys[partner];
                bool up = ((tid & k) == 0);
                bool sw = up ? (a0 < a1) : (a0 > a1);
                if (sw) { keys[tid] = a1; keys[partner] = a0; }
            }
            __syncthreads();
        }
    }
    float sval = -1.0f;
    if (tid < KSEL) {
        uint64_t key = keys[tid];
        int a = 0xFFFF - (int)(key & 0xFFFFu);
        size_t gi = (size_t)b * A_NUM + a;
        float s = scores[gi];
        int   c = classes[gi];
        const float* an = anchors + (size_t)a * 4;
        const float* rg = regression + gi * 4;
        float y1a = an[0], x1a = an[1], y2a = an[2], x2a = an[3];
        float ya = (y1a + y2a) * 0.5f, xa = (x1a + x2a) * 0.5f;
        float ha = y2a - y1a,          wa = x2a - x1a;
        float r0 = rg[0], r1 = rg[1], r2 = rg[2], r3 = rg[3];
        float w  = expf(r3) * wa;
        float h  = expf(r2) * ha;
        float yc = r0 * ha + ya;
        float xc = r1 * wa + xa;
        float x1 = fmaxf(xc - w * 0.5f, 0.0f);
        float y1 = fmaxf(yc - h * 0.5f, 0.0f);
        float x2 = fminf(xc + w * 0.5f, IMG_F);
        float y2 = fminf(yc + h * 0.5f, IMG_F);
        int o = b * KSEL + tid;
        out[(size_t)o * 4 + 0] = x1;
        out[(size_t)o * 4 + 1] = y1;
        out[(size_t)o * 4 + 2] = x2;
        out[(size_t)o * 4 + 3] = y2;
        out[BATCH * KSEL * 4 + o]                = s;
        out[BATCH * KSEL * 4 + BATCH * KSEL + o] = (float)(c + 1);
        sval = s;
    }
    unsigned long long vm = __ballot(sval > SCORE_T);
    if ((tid & 63) == 0) validw[b * 16 + (tid >> 6)] = vm;
}

// ---- suppression bitmask matrix: sup[b][i][w] over j-word w (j>i, same class, iou>T)
__global__ void __launch_bounds__(256) supmat_kernel(const float* __restrict__ out,
                                                     uint64_t* __restrict__ supmat) {
    __shared__ float4 sbox[KSEL];
    __shared__ float  sarea[KSEL];
    __shared__ int    scls[KSEL];
    const int g    = blockIdx.x;       // 0..62 (16 i's each)
    const int b    = blockIdx.y;
    const int tid  = threadIdx.x;
    const int lane = tid & 63;
    const int wv   = tid >> 6;
    const int label_off = BATCH * KSEL * 4 + BATCH * KSEL;
    for (int j = tid; j < KSEL; j += 256) {
        float4 v = *reinterpret_cast<const float4*>(out + (size_t)(b * KSEL + j) * 4);
        sbox[j]  = v;
        sarea[j] = (v.z - v.x) * (v.w - v.y);
        scls[j]  = (int)out[label_off + b * KSEL + j];
    }
    __syncthreads();
    #pragma unroll
    for (int q = 0; q < 4; ++q) {
        int i = g * 16 + wv * 4 + q;
        if (i >= KSEL) continue;                 // wave-uniform
        float4 bi = sbox[i];
        float  ai = sarea[i];
        int    ci = scls[i];
        uint64_t* dst = supmat + ((size_t)b * 1024 + i) * 16;
        #pragma unroll
        for (int w = 0; w < 16; ++w) {
            int j = w * 64 + lane;
            bool sup = false;
            if (j > i && j < KSEL) {
                float4 bj = sbox[j];
                float lx = fmaxf(bi.x, bj.x), ly = fmaxf(bi.y, bj.y);
                float rx = fminf(bi.z, bj.z), ry = fminf(bi.w, bj.w);
                float iw = fmaxf(rx - lx, 0.0f), ih = fmaxf(ry - ly, 0.0f);
                float inter = iw * ih;
                float iou = inter / (ai + sarea[j] - inter + 1e-8f);
                sup = (iou > IOU_T) && (ci == scls[j]);
            }
            unsigned long long m = __ballot(sup);
            if (lane == 0) dst[w] = m;
        }
    }
}

// ---- serial greedy scan, one wave per image, no barriers
__global__ void __launch_bounds__(64) nms_scan_kernel(const uint64_t* __restrict__ supmat,
                                                      const uint64_t* __restrict__ validw,
                                                      float* __restrict__ out) {
    const int b    = blockIdx.x;
    const int lane = threadIdx.x;
    const int w16  = lane & 15;
    uint64_t keep = validw[b * 16 + w16];
    const uint64_t* row = supmat + (size_t)b * 1024 * 16;
    uint64_t pre[16];
    #pragma unroll
    for (int d = 0; d < 16; ++d) pre[d] = row[(size_t)d * 16 + w16];
    for (int base = 0; base < KSEL; base += 16) {
        #pragma unroll
        for (int d = 0; d < 16; ++d) {
            int i = base + d;
            uint64_t kw = __shfl(keep, i >> 6);
            if (i < KSEL && ((kw >> (i & 63)) & 1ull))
                keep &= ~pre[d];
            pre[d] = row[(size_t)(base + 16 + d) * 16 + w16];
        }
    }
    const int keep_off = BATCH * KSEL * 4 + 2 * BATCH * KSEL;
    #pragma unroll
    for (int it = 0; it < 16; ++it) {
        int j = it * 64 + lane;
        uint64_t kw = __shfl(keep, it);
        if (j < KSEL)
            out[keep_off + b * KSEL + j] = ((kw >> lane) & 1ull) ? 1.0f : 0.0f;
    }
}

extern "C" void kernel_launch(void* const* d_in, const int* in_sizes, int n_in,
                              void* d_out, int out_size, void* d_ws, size_t ws_size,
                              hipStream_t stream) {
    const float* anchors        = (const float*)d_in[1];
    const float* regression     = (const float*)d_in[2];
    const float* classification = (const float*)d_in[3];
    float* out = (float*)d_out;

    char* ws = (char*)d_ws;
    const size_t BA = (size_t)BATCH * A_NUM;          // 392832
    float*    scores   = (float*)ws;                  // 1,571,328 B
    int*      classes  = (int*)(ws + 1571328);        // 1,571,328 B -> 3,142,656
    uint64_t* selkeys  = (uint64_t*)(ws + 3142656);   // 65,536 B   -> 3,208,192
    uint32_t* prefix1  = (uint32_t*)(ws + 3208192);   // 256 B
    uint32_t* target2  = (uint32_t*)(ws + 3208448);   // 256 B
    uint32_t* thr32    = (uint32_t*)(ws + 3208704);   // 256 B
    int*      counters = (int*)(ws + 3208960);        // 2,048 B (8 x 256B lines)
    uint64_t* validw   = (uint64_t*)(ws + 3211008);   // 1,024 B  -> 3,212,032
    uint64_t* supmat   = (uint64_t*)(ws + 3212032);   // 1,048,576 B -> 4,260,608
    uint32_t* ghist1   = (uint32_t*)(ws + 4260608);   // 2,097,152 B -> 6,357,760
    uint32_t* ghist2   = (uint32_t*)(ws + 6357760);   // 2,097,152 B -> 8,454,912

    int nblk = (int)((BA + 255) / 256);
    score_kernel<<<nblk, 256, 0, stream>>>(classification, scores, classes,
                                           (uint4*)ghist1);  // zeroes ghist1+ghist2
    hist_kernel<1><<<BATCH * HBLK, 1024, 0, stream>>>(scores, nullptr, ghist1);
    hscan_kernel<1><<<BATCH, 1024, 0, stream>>>(ghist1, nullptr, nullptr,
                                                prefix1, target2, nullptr, nullptr);
    hist_kernel<2><<<BATCH * HBLK, 1024, 0, stream>>>(scores, prefix1, ghist2);
    hscan_kernel<2><<<BATCH, 1024, 0, stream>>>(ghist2, target2, prefix1,
                                                thr32, nullptr, selkeys, counters);
    compact_kernel<<<dim3(48, BATCH), 1024, 0, stream>>>(scores, thr32, counters, selkeys);
    sort_emit_kernel<<<BATCH, 1024, 0, stream>>>(selkeys, scores, classes, anchors,
                                                 regression, out, validw);
    supmat_kernel<<<dim3(63, BATCH), 256, 0, stream>>>(out, supmat);
    nms_scan_kernel<<<BATCH, 64, 0, stream>>>(supmat, validw, out);
}